// Round 3
// baseline (77.825 us; speedup 1.0000x reference)
//
#include <hip/hip_runtime.h>

// DynamicKoopmanOperator:
//   h    = tanh(x @ W1 + b1)                      [B,K]
//   eigs = (h @ W2 + b2)                          [B,K], pairs (mu, om)
//   preds[b,t] = (exp(mu dt) e^{i om dt})^{t+1} applied pairwise to x[b]
//
// Kernel A (MLP): no LDS. x/h read via wave-UNIFORM addresses -> compiler
//   emits scalar (s_load) through K$, leaving VALU purely for FMAs.
// Kernel B (rollout): closed-form seed at t0 kills the serial T dependency;
//   2 pairs/lane -> float4 nontemporal stores (1 KiB per wave per instr).

#define DT_CONST 0.01f

typedef float f32x4 __attribute__((ext_vector_type(4)));   // clang vector: OK for nontemporal builtins

constexpr int KDIM  = 256;
constexpr int AROWS = 4;     // batch rows per MLP block  -> 256 blocks
constexpr int RROWS = 4;     // batch rows per rollout block (1 wave each)
constexpr int CHUNK = 64;    // timesteps per rollout block

// ---------------- Kernel A: MLP -> coefdt[b][k] = eig[b][k] * dt ------------
__global__ __launch_bounds__(256) void koopman_mlp(
    const float* __restrict__ x,  const float* __restrict__ W1,
    const float* __restrict__ b1, const float* __restrict__ W2,
    const float* __restrict__ b2, float* __restrict__ h_ws,
    float* __restrict__ coefdt)
{
    const int j  = threadIdx.x;        // output column 0..255
    const int b0 = blockIdx.x * AROWS;

    float acc[AROWS];

    // GEMM 1 + tanh -> h_ws (global scratch; block-local rows)
    {
        float bj = b1[j];
#pragma unroll
        for (int r = 0; r < AROWS; ++r) acc[r] = bj;
        const float* xb = x + (size_t)b0 * KDIM;   // uniform-addr -> s_load
#pragma unroll 8
        for (int k = 0; k < KDIM; ++k) {
            float wk = W1[(size_t)k * KDIM + j];   // coalesced vector load
#pragma unroll
            for (int r = 0; r < AROWS; ++r)
                acc[r] = fmaf(xb[r * KDIM + k], wk, acc[r]);
        }
#pragma unroll
        for (int r = 0; r < AROWS; ++r)
            h_ws[(size_t)(b0 + r) * KDIM + j] = tanhf(acc[r]);
    }
    __syncthreads();   // drains vmcnt -> h rows visible to this block's reads

    // GEMM 2 -> coefdt (pre-scaled by dt, natural k-order: mu,om interleaved)
    {
        float bj = b2[j];
#pragma unroll
        for (int r = 0; r < AROWS; ++r) acc[r] = bj;
        const float* hb = h_ws + (size_t)b0 * KDIM;  // uniform-addr -> s_load
#pragma unroll 8
        for (int k = 0; k < KDIM; ++k) {
            float wk = W2[(size_t)k * KDIM + j];
#pragma unroll
            for (int r = 0; r < AROWS; ++r)
                acc[r] = fmaf(hb[r * KDIM + k], wk, acc[r]);
        }
#pragma unroll
        for (int r = 0; r < AROWS; ++r)
            coefdt[(size_t)(b0 + r) * KDIM + j] = acc[r] * DT_CONST;
    }
}

// ---------------- Kernel B: rollout, f32x4 nt stores ------------------------
__global__ __launch_bounds__(256) void koopman_rollout(
    const float* __restrict__ x, const float* __restrict__ coefdt,
    float* __restrict__ out, int T)
{
    const int wave = threadIdx.x >> 6;            // wave = one batch row
    const int lane = threadIdx.x & 63;            // lane = 2 pairs (4 elems)
    const int b    = blockIdx.x * RROWS + wave;
    const int t0   = blockIdx.y * CHUNK;

    const f32x4 c  = *reinterpret_cast<const f32x4*>(coefdt + (size_t)b * KDIM + lane * 4);
    const f32x4 xv = *reinterpret_cast<const f32x4*>(x      + (size_t)b * KDIM + lane * 4);
    // c = (mu0*dt, om0*dt, mu1*dt, om1*dt)

    // seed z = M^{t0} x (closed form)
    const float tf = (float)t0;
    float s, co, e;
    e = expf(c.x * tf); sincosf(c.y * tf, &s, &co);
    float z0 = e * (co * xv.x - s * xv.y);
    float z1 = e * (s * xv.x + co * xv.y);
    e = expf(c.z * tf); sincosf(c.w * tf, &s, &co);
    float z2 = e * (co * xv.z - s * xv.w);
    float z3 = e * (s * xv.z + co * xv.w);

    // per-step multipliers
    e = expf(c.x); sincosf(c.y, &s, &co);
    const float a0 = e * co, g0 = e * s;
    e = expf(c.z); sincosf(c.w, &s, &co);
    const float a1 = e * co, g1 = e * s;

    f32x4* orow = reinterpret_cast<f32x4*>(out + ((size_t)b * T + t0) * KDIM) + lane;
    const int nt = ((t0 + CHUNK < T) ? CHUNK : (T - t0));
#pragma unroll 4
    for (int t = 0; t < nt; ++t) {
        float n0 = a0 * z0 - g0 * z1;
        float n1 = g0 * z0 + a0 * z1;
        float n2 = a1 * z2 - g1 * z3;
        float n3 = g1 * z2 + a1 * z3;
        f32x4 v = { n0, n1, n2, n3 };
        __builtin_nontemporal_store(v, orow);
        orow += KDIM / 4;                          // next timestep, 1 KiB row
        z0 = n0; z1 = n1; z2 = n2; z3 = n3;
    }
}

// ---------------- launcher ---------------------------------------------------
extern "C" void kernel_launch(void* const* d_in, const int* in_sizes, int n_in,
                              void* d_out, int out_size, void* d_ws, size_t ws_size,
                              hipStream_t stream) {
    const float* x  = (const float*)d_in[0];
    const float* W1 = (const float*)d_in[1];
    const float* b1 = (const float*)d_in[2];
    const float* W2 = (const float*)d_in[3];
    const float* b2 = (const float*)d_in[4];

    const int Kd = in_sizes[2];                 // 256
    const int Bb = in_sizes[0] / Kd;            // 1024
    const int T  = out_size / (Bb * Kd);        // 256
    const size_t BK = (size_t)Bb * Kd;

    float* out = (float*)d_out;

    // scratch: coef must NOT live in d_out (rollout would race overwriting it).
    float* coefdt;
    float* h_ws;
    if (ws_size >= 2 * BK * sizeof(float)) {
        coefdt = (float*)d_ws;
        h_ws   = (float*)d_ws + BK;
    } else {
        coefdt = (float*)d_ws;                  // 1 MiB, proven available
        h_ws   = out + (out_size - BK);         // d_out tail; dead before rollout
    }

    koopman_mlp<<<Bb / AROWS, 256, 0, stream>>>(x, W1, b1, W2, b2, h_ws, coefdt);

    dim3 grid(Bb / RROWS, (T + CHUNK - 1) / CHUNK);
    koopman_rollout<<<grid, 256, 0, stream>>>(x, coefdt, out, T);
}

// Round 4
// 71.712 us; speedup vs baseline: 1.0852x; 1.0852x over previous
//
#include <hip/hip_runtime.h>

// DynamicKoopmanOperator:
//   h    = tanh(x @ W1 + b1)                      [B,K]
//   eigs = (h @ W2 + b2)                          [B,K], pairs (mu, om)
//   preds[b,t] = (exp(mu dt) e^{i om dt})^{t+1} applied pairwise to x[b]
//
// Kernel A (MLP): x read via wave-uniform addresses (read-only -> s_load);
//   h staged in LDS, read back as uniform ds_read_b128 (broadcast, 4 k/read).
// Kernel B (rollout): closed-form seed at t0 kills the serial T dependency;
//   plain (through-L2) f32x4 stores — mimics fillBuffer's 7.08 TB/s pattern.
//   NT stores measured WORSE (R2: 77.8 vs R1: 72.2 µs) — L2 write
//   aggregation wins for streaming stores on this chip.

#define DT_CONST 0.01f

typedef float f32x4 __attribute__((ext_vector_type(4)));

constexpr int KDIM  = 256;
constexpr int AROWS = 4;     // batch rows per MLP block  -> 256 blocks
constexpr int RROWS = 4;     // batch rows per rollout block (1 wave each)
constexpr int CHUNK = 32;    // timesteps per rollout block -> 2048 blocks

// ---------------- Kernel A: MLP -> coefdt[b][k] = eig[b][k] * dt ------------
__global__ __launch_bounds__(256) void koopman_mlp(
    const float* __restrict__ x,  const float* __restrict__ W1,
    const float* __restrict__ b1, const float* __restrict__ W2,
    const float* __restrict__ b2, float* __restrict__ coefdt)
{
    __shared__ alignas(16) float hs[AROWS][KDIM];   // tanh hidden, 4 KiB

    const int j  = threadIdx.x;        // output column 0..255
    const int b0 = blockIdx.x * AROWS;

    float acc[AROWS];

    // GEMM 1 + tanh -> LDS. x addr is wave-uniform & read-only -> s_load.
    {
        float bj = b1[j];
#pragma unroll
        for (int r = 0; r < AROWS; ++r) acc[r] = bj;
        const float* xb = x + (size_t)b0 * KDIM;
#pragma unroll 8
        for (int k = 0; k < KDIM; ++k) {
            float wk = W1[(size_t)k * KDIM + j];   // coalesced, L2-resident
#pragma unroll
            for (int r = 0; r < AROWS; ++r)
                acc[r] = fmaf(xb[r * KDIM + k], wk, acc[r]);
        }
#pragma unroll
        for (int r = 0; r < AROWS; ++r) hs[r][j] = tanhf(acc[r]);
    }
    __syncthreads();

    // GEMM 2: h via uniform ds_read_b128 (broadcast, conflict-free).
    {
        float bj = b2[j];
#pragma unroll
        for (int r = 0; r < AROWS; ++r) acc[r] = bj;
#pragma unroll 2
        for (int k4 = 0; k4 < KDIM / 4; ++k4) {
            f32x4 hv[AROWS];
#pragma unroll
            for (int r = 0; r < AROWS; ++r)
                hv[r] = *reinterpret_cast<const f32x4*>(&hs[r][k4 * 4]);
#pragma unroll
            for (int i = 0; i < 4; ++i) {
                float wk = W2[(size_t)(k4 * 4 + i) * KDIM + j];
#pragma unroll
                for (int r = 0; r < AROWS; ++r)
                    acc[r] = fmaf(hv[r][i], wk, acc[r]);
            }
        }
#pragma unroll
        for (int r = 0; r < AROWS; ++r)
            coefdt[(size_t)(b0 + r) * KDIM + j] = acc[r] * DT_CONST;
    }
}

// ---------------- Kernel B: rollout, plain f32x4 stores ---------------------
__global__ __launch_bounds__(256) void koopman_rollout(
    const float* __restrict__ x, const float* __restrict__ coefdt,
    float* __restrict__ out, int T)
{
    const int wave = threadIdx.x >> 6;            // wave = one batch row
    const int lane = threadIdx.x & 63;            // lane = 2 pairs (4 elems)
    const int b    = blockIdx.x * RROWS + wave;
    const int t0   = blockIdx.y * CHUNK;

    const f32x4 c  = *reinterpret_cast<const f32x4*>(coefdt + (size_t)b * KDIM + lane * 4);
    const f32x4 xv = *reinterpret_cast<const f32x4*>(x      + (size_t)b * KDIM + lane * 4);
    // c = (mu0*dt, om0*dt, mu1*dt, om1*dt)

    // seed z = M^{t0} x (closed form)
    const float tf = (float)t0;
    float s, co, e;
    e = expf(c.x * tf); sincosf(c.y * tf, &s, &co);
    float z0 = e * (co * xv.x - s * xv.y);
    float z1 = e * (s * xv.x + co * xv.y);
    e = expf(c.z * tf); sincosf(c.w * tf, &s, &co);
    float z2 = e * (co * xv.z - s * xv.w);
    float z3 = e * (s * xv.z + co * xv.w);

    // per-step multipliers (two independent chains -> ILP in the loop)
    e = expf(c.x); sincosf(c.y, &s, &co);
    const float a0 = e * co, g0 = e * s;
    e = expf(c.z); sincosf(c.w, &s, &co);
    const float a1 = e * co, g1 = e * s;

    f32x4* orow = reinterpret_cast<f32x4*>(out + ((size_t)b * T + t0) * KDIM) + lane;
    const int nt = ((t0 + CHUNK < T) ? CHUNK : (T - t0));
#pragma unroll 4
    for (int t = 0; t < nt; ++t) {
        float n0 = a0 * z0 - g0 * z1;
        float n1 = g0 * z0 + a0 * z1;
        float n2 = a1 * z2 - g1 * z3;
        float n3 = g1 * z2 + a1 * z3;
        f32x4 v = { n0, n1, n2, n3 };
        *orow = v;                                 // plain store, through L2
        orow += KDIM / 4;                          // next timestep, 1 KiB row
        z0 = n0; z1 = n1; z2 = n2; z3 = n3;
    }
}

// ---------------- launcher ---------------------------------------------------
extern "C" void kernel_launch(void* const* d_in, const int* in_sizes, int n_in,
                              void* d_out, int out_size, void* d_ws, size_t ws_size,
                              hipStream_t stream) {
    const float* x  = (const float*)d_in[0];
    const float* W1 = (const float*)d_in[1];
    const float* b1 = (const float*)d_in[2];
    const float* W2 = (const float*)d_in[3];
    const float* b2 = (const float*)d_in[4];

    const int Kd = in_sizes[2];                 // 256
    const int Bb = in_sizes[0] / Kd;            // 1024
    const int T  = out_size / (Bb * Kd);        // 256

    float* coefdt = (float*)d_ws;               // B*K floats = 1 MiB
    float* out    = (float*)d_out;

    koopman_mlp<<<Bb / AROWS, 256, 0, stream>>>(x, W1, b1, W2, b2, coefdt);

    dim3 grid(Bb / RROWS, (T + CHUNK - 1) / CHUNK);
    koopman_rollout<<<grid, 256, 0, stream>>>(x, coefdt, out, T);
}

// Round 5
// 64.734 us; speedup vs baseline: 1.2022x; 1.1078x over previous
//
#include <hip/hip_runtime.h>

// DynamicKoopmanOperator:
//   h    = tanh(x @ W1 + b1)                      [B,K]
//   eigs = (h @ W2 + b2)                          [B,K], pairs (mu, om)
//   preds[b,t] = (exp(mu dt) e^{i om dt})^{t+1} applied pairwise to x[b]
//
// R4 changes (R1/R3 both ~72us despite different micro-structure):
//  - MLP: k-split-2, 512-thread blocks -> 8 waves/CU (was 1 wave/SIMD, zero
//    latency hiding on L2 W-loads). Same 128 MiB W traffic.
//  - Rollout: 2 independent batch-row chains per wave -> 2 independent 1 KiB
//    stores per iter (fillBuffer hits 7 TB/s at 10.7% occupancy via in-flight
//    INDEPENDENT stores; our single serial z-chain may throttle the stream).

#define DT_CONST 0.01f

typedef float f32x4 __attribute__((ext_vector_type(4)));

constexpr int KDIM  = 256;
constexpr int KHALF = 128;   // k-split factor 2
constexpr int AROWS = 4;     // batch rows per MLP block  -> 256 blocks x 512 thr
constexpr int RROWS = 8;     // batch rows per rollout block (2 per wave)
constexpr int CHUNK = 32;    // timesteps per rollout block -> grid (128, 8)

// ---------------- Kernel A: MLP -> coefdt[b][k] = eig[b][k] * dt ------------
__global__ __launch_bounds__(512) void koopman_mlp(
    const float* __restrict__ x,  const float* __restrict__ W1,
    const float* __restrict__ b1, const float* __restrict__ W2,
    const float* __restrict__ b2, float* __restrict__ coefdt)
{
    __shared__ alignas(16) float part[2][AROWS][KDIM];  // 8 KiB partials
    __shared__ alignas(16) float hs[AROWS][KDIM];       // 4 KiB hidden

    const int tid = threadIdx.x;
    const int j   = tid & (KDIM - 1);       // output column 0..255
    const int kh  = tid >> 8;               // k-half 0/1 (wave-uniform)
    const int b0  = blockIdx.x * AROWS;

    float acc[AROWS];

    // GEMM 1 partial: k in [kh*128, kh*128+128)
    {
#pragma unroll
        for (int r = 0; r < AROWS; ++r) acc[r] = 0.f;
        const float* xb = x + (size_t)b0 * KDIM + kh * KHALF;  // uniform -> s_load
        const float* w  = W1 + (size_t)kh * KHALF * KDIM + j;
#pragma unroll 8
        for (int k = 0; k < KHALF; ++k) {
            float wk = w[(size_t)k * KDIM];        // coalesced, L2-resident
#pragma unroll
            for (int r = 0; r < AROWS; ++r)
                acc[r] = fmaf(xb[r * KDIM + k], wk, acc[r]);
        }
#pragma unroll
        for (int r = 0; r < AROWS; ++r) part[kh][r][j] = acc[r];
    }
    __syncthreads();
    if (kh == 0) {
#pragma unroll
        for (int r = 0; r < AROWS; ++r)
            hs[r][j] = tanhf(part[0][r][j] + part[1][r][j] + b1[j]);
    }
    __syncthreads();

    // GEMM 2 partial: h via uniform ds_read_b128 (broadcast, 4 k per read)
    {
#pragma unroll
        for (int r = 0; r < AROWS; ++r) acc[r] = 0.f;
        const float* w = W2 + (size_t)kh * KHALF * KDIM + j;
#pragma unroll 2
        for (int k4 = 0; k4 < KHALF / 4; ++k4) {
            f32x4 hv[AROWS];
#pragma unroll
            for (int r = 0; r < AROWS; ++r)
                hv[r] = *reinterpret_cast<const f32x4*>(&hs[r][kh * KHALF + k4 * 4]);
#pragma unroll
            for (int i = 0; i < 4; ++i) {
                float wk = w[(size_t)(k4 * 4 + i) * KDIM];
#pragma unroll
                for (int r = 0; r < AROWS; ++r)
                    acc[r] = fmaf(hv[r][i], wk, acc[r]);
            }
        }
#pragma unroll
        for (int r = 0; r < AROWS; ++r) part[kh][r][j] = acc[r];
    }
    __syncthreads();
    if (kh == 0) {
#pragma unroll
        for (int r = 0; r < AROWS; ++r)
            coefdt[(size_t)(b0 + r) * KDIM + j] =
                (part[0][r][j] + part[1][r][j] + b2[j]) * DT_CONST;
    }
}

// ---------------- Kernel B: rollout, 2 independent chains per wave ----------
__global__ __launch_bounds__(256) void koopman_rollout(
    const float* __restrict__ x, const float* __restrict__ coefdt,
    float* __restrict__ out, int T)
{
    const int wave = threadIdx.x >> 6;
    const int lane = threadIdx.x & 63;            // lane = 2 pairs (4 elems)
    const int bA   = blockIdx.x * RROWS + wave;   // chain A row
    const int bB   = bA + 4;                      // chain B row (independent)
    const int t0   = blockIdx.y * CHUNK;

    const f32x4 cA = *reinterpret_cast<const f32x4*>(coefdt + (size_t)bA * KDIM + lane * 4);
    const f32x4 xA = *reinterpret_cast<const f32x4*>(x      + (size_t)bA * KDIM + lane * 4);
    const f32x4 cB = *reinterpret_cast<const f32x4*>(coefdt + (size_t)bB * KDIM + lane * 4);
    const f32x4 xB = *reinterpret_cast<const f32x4*>(x      + (size_t)bB * KDIM + lane * 4);

    const float tf = (float)t0;
    float s, co, e;

    // seeds z = M^{t0} x (closed form) and per-step multipliers, chain A
    e = expf(cA.x * tf); sincosf(cA.y * tf, &s, &co);
    float zA0 = e * (co * xA.x - s * xA.y), zA1 = e * (s * xA.x + co * xA.y);
    e = expf(cA.z * tf); sincosf(cA.w * tf, &s, &co);
    float zA2 = e * (co * xA.z - s * xA.w), zA3 = e * (s * xA.z + co * xA.w);
    e = expf(cA.x); sincosf(cA.y, &s, &co);
    const float aA0 = e * co, gA0 = e * s;
    e = expf(cA.z); sincosf(cA.w, &s, &co);
    const float aA1 = e * co, gA1 = e * s;

    // chain B
    e = expf(cB.x * tf); sincosf(cB.y * tf, &s, &co);
    float zB0 = e * (co * xB.x - s * xB.y), zB1 = e * (s * xB.x + co * xB.y);
    e = expf(cB.z * tf); sincosf(cB.w * tf, &s, &co);
    float zB2 = e * (co * xB.z - s * xB.w), zB3 = e * (s * xB.z + co * xB.w);
    e = expf(cB.x); sincosf(cB.y, &s, &co);
    const float aB0 = e * co, gB0 = e * s;
    e = expf(cB.z); sincosf(cB.w, &s, &co);
    const float aB1 = e * co, gB1 = e * s;

    f32x4* oA = reinterpret_cast<f32x4*>(out + ((size_t)bA * T + t0) * KDIM) + lane;
    f32x4* oB = reinterpret_cast<f32x4*>(out + ((size_t)bB * T + t0) * KDIM) + lane;
    const int nt = ((t0 + CHUNK < T) ? CHUNK : (T - t0));
#pragma unroll 4
    for (int t = 0; t < nt; ++t) {
        float nA0 = aA0 * zA0 - gA0 * zA1;
        float nA1 = gA0 * zA0 + aA0 * zA1;
        float nA2 = aA1 * zA2 - gA1 * zA3;
        float nA3 = gA1 * zA2 + aA1 * zA3;
        float nB0 = aB0 * zB0 - gB0 * zB1;
        float nB1 = gB0 * zB0 + aB0 * zB1;
        float nB2 = aB1 * zB2 - gB1 * zB3;
        float nB3 = gB1 * zB2 + aB1 * zB3;
        f32x4 vA = { nA0, nA1, nA2, nA3 };
        f32x4 vB = { nB0, nB1, nB2, nB3 };
        *oA = vA;                                  // two independent 1 KiB
        *oB = vB;                                  // wave-stores back-to-back
        oA += KDIM / 4; oB += KDIM / 4;
        zA0 = nA0; zA1 = nA1; zA2 = nA2; zA3 = nA3;
        zB0 = nB0; zB1 = nB1; zB2 = nB2; zB3 = nB3;
    }
}

// ---------------- launcher ---------------------------------------------------
extern "C" void kernel_launch(void* const* d_in, const int* in_sizes, int n_in,
                              void* d_out, int out_size, void* d_ws, size_t ws_size,
                              hipStream_t stream) {
    const float* x  = (const float*)d_in[0];
    const float* W1 = (const float*)d_in[1];
    const float* b1 = (const float*)d_in[2];
    const float* W2 = (const float*)d_in[3];
    const float* b2 = (const float*)d_in[4];

    const int Kd = in_sizes[2];                 // 256
    const int Bb = in_sizes[0] / Kd;            // 1024
    const int T  = out_size / (Bb * Kd);        // 256

    float* coefdt = (float*)d_ws;               // B*K floats = 1 MiB
    float* out    = (float*)d_out;

    koopman_mlp<<<Bb / AROWS, 512, 0, stream>>>(x, W1, b1, W2, b2, coefdt);

    dim3 grid(Bb / RROWS, (T + CHUNK - 1) / CHUNK);
    koopman_rollout<<<grid, 256, 0, stream>>>(x, coefdt, out, T);
}